// Round 7
// baseline (148.403 us; speedup 1.0000x reference)
//
#include <hip/hip_runtime.h>
#include <hip/hip_fp16.h>

#define BB    32
#define CIN   256
#define COUT  256
#define HH    28
#define WW    28
#define NPIX  784
#define HP    30
#define WP    30

#define BM    64
#define BN    128
#define NT    6               // 6 N-tiles: nt 0..4 = 128 px, nt 5 = 144 px

// workspace:
//   wgen2: fragment-ordered filters (16x16x32 MFMA), per (b,mtH) slice
//          294912 f16. Chunk (8 f16): (c32*9+khw)*512 + sub*64 + quad*16 + col
//          holds A[m = mtH*128 + sub*16 + col][ch = c32*32 + quad*8 .. +7]
//   xpad : [b][30][30][256] f16 zero-padded NHWC
#define SLICE_ELEMS 294912                       // 128 * 2304
#define WGEN_ELEMS  ((size_t)BB * 2 * SLICE_ELEMS)
#define XPAD_OFF    (WGEN_ELEMS)

#define PREP_GENW  512        // (og 0..31) x (c32 0..7) x (bh 0..1)
#define PREP_GENX  960
#define PREP_GRID  (PREP_GENW + PREP_GENX)

typedef _Float16 f16x8 __attribute__((ext_vector_type(8)));
typedef float    f32x4 __attribute__((ext_vector_type(4)));

static __device__ __forceinline__ ushort f2h_bits(float v) {
    __half h = __float2half(v);
    return *reinterpret_cast<ushort*>(&h);
}

static __device__ __forceinline__ void gll16(const ushort* g, ushort* l) {
    __builtin_amdgcn_global_load_lds(
        (const __attribute__((address_space(1))) unsigned int*)g,
        (__attribute__((address_space(3))) unsigned int*)l, 16, 0, 0);
}

#define KOFF(k) (((k) / 3) * 30 + ((k) % 3))

// ---------------------------------------------------------------------------
// Fused prep kernel (unchanged).
// ---------------------------------------------------------------------------
__global__ __launch_bounds__(256) void prep(const float* __restrict__ weight,
                                            const float* __restrict__ se,
                                            const float* __restrict__ x,
                                            ushort* __restrict__ wgen2,
                                            ushort* __restrict__ xpad) {
    __shared__ __align__(16) char smem[29696];
    const int bid = blockIdx.x;
    const int tid = threadIdx.x;

    if (bid < PREP_GENW) {
        // ---- gen_w V5 ----
        const int og  = bid >> 4;
        const int bh  = (bid >> 3) & 1;
        const int c32 = bid & 7;
        const int ol  = tid >> 5;
        const int cl  = tid & 31;
        const int o   = og * 8 + ol;
        const int c   = c32 * 32 + cl;
        const int mtH = og >> 4;

        float*  se_sh = (float*)smem;                  // 1024 B
        ushort* w_lds = (ushort*)(smem + 1024);        // 2 x 2880 ushort

        se_sh[tid] = se[tid];

        float4 wr[18];
        const float4* wp = (const float4*)(weight + ((size_t)o * CIN + c) * 72);
#pragma unroll
        for (int i = 0; i < 18; ++i) wr[i] = wp[i];

        const int khw0 = tid >> 5;
        const int r0   = tid & 31;
        const int q0   = r0 >> 3;
        const int ol0  = r0 & 7;
        const int o0   = og * 8 + ol0;
        const int sub0 = (o0 >> 4) & 7, col0 = o0 & 15;
        const int dst0 = ((c32 * 9 + khw0) * 512 + sub0 * 64 + q0 * 16 + col0) * 8;
        const int src0 = (khw0 * 8 + ol0) * 40 + q0 * 8;
        const int q1   = tid >> 3;
        const int ol1  = tid & 7;
        const int o1   = og * 8 + ol1;
        const int sub1 = (o1 >> 4) & 7, col1 = o1 & 15;
        const int dst1 = ((c32 * 9 + 8) * 512 + sub1 * 64 + q1 * 16 + col1) * 8;
        const int src1 = (8 * 8 + ol1) * 40 + q1 * 8;

        __syncthreads();

        for (int bi = 0; bi < 16; ++bi) {
            const int b   = bh * 16 + bi;
            const int buf = (bi & 1) * 2880;
            const float s0 = se_sh[b * 8 + 0], s1 = se_sh[b * 8 + 1];
            const float s2 = se_sh[b * 8 + 2], s3 = se_sh[b * 8 + 3];
            const float s4 = se_sh[b * 8 + 4], s5 = se_sh[b * 8 + 5];
            const float s6 = se_sh[b * 8 + 6], s7 = se_sh[b * 8 + 7];
#pragma unroll
            for (int k = 0; k < 9; ++k) {
                const float4 w0 = wr[2 * k + 0];
                const float4 w1 = wr[2 * k + 1];
                const float v = w0.x * s0 + w0.y * s1 + w0.z * s2 + w0.w * s3
                              + w1.x * s4 + w1.y * s5 + w1.z * s6 + w1.w * s7;
                w_lds[buf + (k * 8 + ol) * 40 + cl] = f2h_bits(v);
            }
            __syncthreads();
            ushort* slice_base = wgen2 + (size_t)(b * 2 + mtH) * SLICE_ELEMS;
            *(uint4*)(slice_base + dst0) = *(const uint4*)(w_lds + buf + src0);
            if (tid < 32)
                *(uint4*)(slice_base + dst1) = *(const uint4*)(w_lds + buf + src1);
        }
    } else {
        // ---- gen_x ----
        const int idx = bid - PREP_GENW;
        const int hp  = idx % HP;
        const int b   = idx / HP;
        ushort* row = xpad + ((size_t)b * HP + hp) * WP * CIN;

        if (hp == 0 || hp == HP - 1) {
            uint* r32 = (uint*)row;
            for (int i = tid; i < (WP * CIN) / 2; i += 256) r32[i] = 0u;
            return;
        }
        {
            uint* c0 = (uint*)row;
            uint* c1 = (uint*)(row + (WP - 1) * CIN);
            if (tid < 128)       c0[tid] = 0u;
            else                 c1[tid - 128] = 0u;
        }
        float* lds = (float*)smem;
        const int h = hp - 1;
        const float* xr = x + (size_t)b * CIN * NPIX + h * WW;

        for (int f = tid; f < CIN * WW; f += 256) {
            const int cc = f / WW;
            const int w  = f % WW;
            lds[cc * (WW + 1) + w] = xr[(size_t)cc * NPIX + w];
        }
        __syncthreads();
        for (int g2 = tid; g2 < WW * CIN; g2 += 256) {
            const int w  = g2 >> 8;
            const int cc = g2 & 255;
            row[(w + 1) * CIN + cc] = f2h_bits(lds[cc * (WW + 1) + w]);
        }
    }
}

// ---------------------------------------------------------------------------
// dconv tile body — R7 STRUCTURAL change: wave grid 2wm x 2wn  ->  1 x 4wn.
// Each wave owns the FULL block M=64 (mi 0..3) and N = NFR*16 px.
// Why: in the 2x2 grid, wm-pairs read IDENTICAL B fragments from LDS and
// wn-pairs read IDENTICAL A fragments from global -- both operand streams
// fetched 2x per block. DS pipe was the longest pole (~20us/CU incl 1.62M
// conflict-cycles vs MFMA 14us). New split HALVES block DS reads (16->8 per
// khw); A-loads per wave double BUT all 4 waves read the same A chunks
// within ~100s of cycles -> L1 serves 3 of 4, L2 traffic ~unchanged.
// acc stays 4x2=32 VGPR; afr ring 3x4, bfr ring 3x2.
// Everything else identical to R5 (measured best): plain-240 + KOFF imms,
// SGB order VMEM->DS->MFMA, __syncthreads per c32, no setprio.
// NFR BLOCK-UNIFORM (barrier safety); nt=5 runs NFR=3 with wave 3 fully
// clamped+masked (px 784..831 OOB).
// ---------------------------------------------------------------------------
template<int NFR>
static __device__ __forceinline__ void conv_tile(
    const ushort* __restrict__ wgen2, const ushort* __restrict__ xpad,
    const float* __restrict__ bias, float* __restrict__ out,
    ushort (*Psh)[7680], int b, int mtH, int mtl, int nt, int no, int tid)
{
    const int lane = tid & 63;
    const int col  = lane & 15;
    const int quad = lane >> 4;

    const int mo   = mtH * 128 + mtl * 64;          // wave-invariant M base
    const int h_lo = (nt * BN) / WW;

    // A fragment pointer: frag mi at K-step st lives at (st<<9) + (mtl*4+mi)*64 + lane
    const f16x8* ag = (const f16x8*)(wgen2 + (size_t)(b * 2 + mtH) * SLICE_ELEMS)
                      + (mtl * 4) * 64 + lane;
    const ushort* xp = xpad + (size_t)b * HP * WP * CIN;

    int p_goff[4], p_loff[4];
    bool p_ok[4];
#pragma unroll
    for (int r = 0; r < 4; ++r) {
        const int j = r * 256 + tid;
        p_ok[r] = (j < 960);
        const int jj  = p_ok[r] ? j : 0;
        const int qc  = jj / 240;
        const int em  = jj % 240;         // identity source mapping (no swizzle)
        const int rr  = em / 30;
        const int ww  = em % 30;
        int srow = h_lo + rr;
        if (srow > 29) srow = 29;
        p_goff[r] = (srow * WP + ww) * CIN + qc * 8;
        p_loff[r] = jj * 8;               // LDS dest lane-linear (gll16 rule)
    }

    int pb[NFR], pst[NFR];
#pragma unroll
    for (int j = 0; j < NFR; ++j) {
        const int p  = no + j * 16 + col;
        pst[j] = p;
        const int pc = p > (NPIX - 1) ? (NPIX - 1) : p;   // clamp masked frags
        pb[j] = quad * 240 + (pc / WW - h_lo) * 30 + (pc % WW);
    }

    f32x4 acc[4][NFR];
#pragma unroll
    for (int mi = 0; mi < 4; ++mi)
#pragma unroll
        for (int nj = 0; nj < NFR; ++nj)
            acc[mi][nj] = (f32x4){0.f, 0.f, 0.f, 0.f};

    // ---- prologue ----
#pragma unroll
    for (int r = 0; r < 4; ++r)
        if (p_ok[r]) gll16(xp + p_goff[r], &Psh[0][p_loff[r]]);

    f16x8 afr[3][4];
#pragma unroll
    for (int mi = 0; mi < 4; ++mi) afr[0][mi] = ag[mi * 64];
    {
        const f16x8* a1 = ag + (1 << 9);
#pragma unroll
        for (int mi = 0; mi < 4; ++mi) afr[1][mi] = a1[mi * 64];
    }

    f16x8 bfr[3][NFR];

    for (int c32 = 0; c32 < 8; ++c32) {
        __syncthreads();   // patch(c32) resident; prev buffer free

        if (c32 < 7) {
            const int nb = (c32 + 1) & 1;
#pragma unroll
            for (int r = 0; r < 4; ++r)
                if (p_ok[r]) gll16(xp + p_goff[r] + (c32 + 1) * 32,
                                   &Psh[nb][p_loff[r]]);
        }

        const f16x8* Pc = (const f16x8*)Psh[c32 & 1];

        // bf ring prologue: slots 0,1 = khw 0,1 (offset-immediate reads)
#pragma unroll
        for (int j = 0; j < NFR; ++j) {
            bfr[0][j] = Pc[pb[j] + KOFF(0)];
            bfr[1][j] = Pc[pb[j] + KOFF(1)];
        }

#pragma unroll
        for (int khw = 0; khw < 9; ++khw) {
            const int st = c32 * 9 + khw;
            // A prefetch, distance 2 (slot khw%3; 9%3==0 keeps ring seamless)
            int sp = st + 2; if (sp > 71) sp = 71;
            const f16x8* apf = ag + ((size_t)sp << 9);
#pragma unroll
            for (int mi = 0; mi < 4; ++mi)
                afr[(khw + 2) % 3][mi] = apf[mi * 64];
            // bf prefetch, distance 2 (within c32)
            if (khw < 7) {
#pragma unroll
                for (int j = 0; j < NFR; ++j)
                    bfr[(khw + 2) % 3][j] = Pc[pb[j] + KOFF(khw + 2)];
            }
            // consume
#pragma unroll
            for (int mi = 0; mi < 4; ++mi)
#pragma unroll
                for (int nj = 0; nj < NFR; ++nj)
                    acc[mi][nj] = __builtin_amdgcn_mfma_f32_16x16x32_f16(
                        afr[khw % 3][mi], bfr[khw % 3][nj], acc[mi][nj], 0, 0, 0);
            // pinned pipeline (R5-proven order): VMEM -> DS -> MFMA
            __builtin_amdgcn_sched_group_barrier(0x020, 4, 0);        // VMEM_READ
            if (khw < 7)
                __builtin_amdgcn_sched_group_barrier(0x100, NFR, 0);  // DS_READ
            __builtin_amdgcn_sched_group_barrier(0x008, 4 * NFR, 0);  // MFMA
        }
    }

    // ---- epilogue (store-masked for clamped fragments) ----
    float* ob = out + (size_t)b * COUT * NPIX;
#pragma unroll
    for (int mi = 0; mi < 4; ++mi) {
        const int m = mo + mi * 16 + quad * 4;
        const float4 bv = *(const float4*)(bias + m);
#pragma unroll
        for (int nj = 0; nj < NFR; ++nj) {
            const int p = pst[nj];
            if (p < NPIX) {
                ob[(size_t)(m + 0) * NPIX + p] = acc[mi][nj][0] + bv.x;
                ob[(size_t)(m + 1) * NPIX + p] = acc[mi][nj][1] + bv.y;
                ob[(size_t)(m + 2) * NPIX + p] = acc[mi][nj][2] + bv.z;
                ob[(size_t)(m + 3) * NPIX + p] = acc[mi][nj][3] + bv.w;
            }
        }
    }
}

// ---------------------------------------------------------------------------
// dconv: grid 768 = exactly 3 blocks/CU. Wave grid is 1x4 (wn only; each
// wave owns full M=64). nt 0..4: NFR=2, no = nt*128 + wn*32. nt=5: NFR=3,
// no = 640 + wn*48 (9 valid frags over waves 0..2; wave 3 fully masked).
// launch_bounds(256,3): regalloc headroom to keep the prefetch rings live.
// ---------------------------------------------------------------------------
__global__ __launch_bounds__(256, 3) void dconv_mfma(const ushort* __restrict__ wgen2,
                                                     const ushort* __restrict__ xpad,
                                                     const float* __restrict__ bias,
                                                     float* __restrict__ out) {
    const int bid    = blockIdx.x;
    const int g      = bid & 7;            // XCD
    const int s      = bid >> 3;           // 0..95
    const int t      = s % 12;
    const int nt     = t % 6;
    const int mtl    = t / 6;
    const int slice2 = g + 8 * (s / 12);   // 0..63 = b*2 + mtH
    const int b      = slice2 >> 1;
    const int mtH    = slice2 & 1;
    const int tid    = threadIdx.x;
    const int wn     = tid >> 6;           // wave index 0..3 = wn

    __shared__ ushort Psh[2][7680];        // 2 x 15360 B

    if (nt == 5)   // block-uniform branch: all 4 waves take the same template
        conv_tile<3>(wgen2, xpad, bias, out, Psh, b, mtH, mtl, nt, 640 + wn * 48, tid);
    else
        conv_tile<2>(wgen2, xpad, bias, out, Psh, b, mtH, mtl, nt,
                     nt * BN + wn * 32, tid);
}

extern "C" void kernel_launch(void* const* d_in, const int* in_sizes, int n_in,
                              void* d_out, int out_size, void* d_ws, size_t ws_size,
                              hipStream_t stream) {
    const float* x      = (const float*)d_in[0];
    const float* se     = (const float*)d_in[1];
    const float* weight = (const float*)d_in[2];
    const float* bias   = (const float*)d_in[3];
    float* out          = (float*)d_out;

    ushort* wgen2 = (ushort*)d_ws;
    ushort* xpad  = (ushort*)d_ws + XPAD_OFF;
    (void)ws_size; (void)in_sizes; (void)n_in; (void)out_size;

    prep<<<dim3(PREP_GRID), dim3(256), 0, stream>>>(weight, se, x, wgen2, xpad);
    dconv_mfma<<<dim3(BB * 4 * NT), dim3(256), 0, stream>>>(wgen2, xpad, bias, out);
}

// Round 8
// 143.149 us; speedup vs baseline: 1.0367x; 1.0367x over previous
//
#include <hip/hip_runtime.h>
#include <hip/hip_fp16.h>

#define BB    32
#define CIN   256
#define COUT  256
#define HH    28
#define WW    28
#define NPIX  784
#define HP    30
#define WP    30

#define BM    64
#define BN    96
#define NT    8               // 8 N-tiles of 96 px (nt7: 112 px, tail masked)

// workspace:
//   wgen2: fragment-ordered filters (16x16x32 MFMA), per (b,mtH) slice
//          294912 f16. Chunk (8 f16): (c32*9+khw)*512 + sub*64 + quad*16 + col
//          holds A[m = mtH*128 + sub*16 + col][ch = c32*32 + quad*8 .. +7]
//   xpad : [b][30][30][256] f16 zero-padded NHWC
#define SLICE_ELEMS 294912                       // 128 * 2304
#define WGEN_ELEMS  ((size_t)BB * 2 * SLICE_ELEMS)
#define XPAD_OFF    (WGEN_ELEMS)

#define PREP_GENW  512        // (og 0..31) x (c32 0..7) x (bh 0..1)
#define PREP_GENX  960
#define PREP_GRID  (PREP_GENW + PREP_GENX)

typedef _Float16 f16x8 __attribute__((ext_vector_type(8)));
typedef float    f32x4 __attribute__((ext_vector_type(4)));

static __device__ __forceinline__ ushort f2h_bits(float v) {
    __half h = __float2half(v);
    return *reinterpret_cast<ushort*>(&h);
}

static __device__ __forceinline__ void gll16(const ushort* g, ushort* l) {
    __builtin_amdgcn_global_load_lds(
        (const __attribute__((address_space(1))) unsigned int*)g,
        (__attribute__((address_space(3))) unsigned int*)l, 16, 0, 0);
}

#define KOFF(k) (((k) / 3) * 30 + ((k) % 3))

// ---------------------------------------------------------------------------
// Fused prep kernel (unchanged).
// ---------------------------------------------------------------------------
__global__ __launch_bounds__(256) void prep(const float* __restrict__ weight,
                                            const float* __restrict__ se,
                                            const float* __restrict__ x,
                                            ushort* __restrict__ wgen2,
                                            ushort* __restrict__ xpad) {
    __shared__ __align__(16) char smem[29696];
    const int bid = blockIdx.x;
    const int tid = threadIdx.x;

    if (bid < PREP_GENW) {
        // ---- gen_w V5 ----
        const int og  = bid >> 4;
        const int bh  = (bid >> 3) & 1;
        const int c32 = bid & 7;
        const int ol  = tid >> 5;
        const int cl  = tid & 31;
        const int o   = og * 8 + ol;
        const int c   = c32 * 32 + cl;
        const int mtH = og >> 4;

        float*  se_sh = (float*)smem;                  // 1024 B
        ushort* w_lds = (ushort*)(smem + 1024);        // 2 x 2880 ushort

        se_sh[tid] = se[tid];

        float4 wr[18];
        const float4* wp = (const float4*)(weight + ((size_t)o * CIN + c) * 72);
#pragma unroll
        for (int i = 0; i < 18; ++i) wr[i] = wp[i];

        const int khw0 = tid >> 5;
        const int r0   = tid & 31;
        const int q0   = r0 >> 3;
        const int ol0  = r0 & 7;
        const int o0   = og * 8 + ol0;
        const int sub0 = (o0 >> 4) & 7, col0 = o0 & 15;
        const int dst0 = ((c32 * 9 + khw0) * 512 + sub0 * 64 + q0 * 16 + col0) * 8;
        const int src0 = (khw0 * 8 + ol0) * 40 + q0 * 8;
        const int q1   = tid >> 3;
        const int ol1  = tid & 7;
        const int o1   = og * 8 + ol1;
        const int sub1 = (o1 >> 4) & 7, col1 = o1 & 15;
        const int dst1 = ((c32 * 9 + 8) * 512 + sub1 * 64 + q1 * 16 + col1) * 8;
        const int src1 = (8 * 8 + ol1) * 40 + q1 * 8;

        __syncthreads();

        for (int bi = 0; bi < 16; ++bi) {
            const int b   = bh * 16 + bi;
            const int buf = (bi & 1) * 2880;
            const float s0 = se_sh[b * 8 + 0], s1 = se_sh[b * 8 + 1];
            const float s2 = se_sh[b * 8 + 2], s3 = se_sh[b * 8 + 3];
            const float s4 = se_sh[b * 8 + 4], s5 = se_sh[b * 8 + 5];
            const float s6 = se_sh[b * 8 + 6], s7 = se_sh[b * 8 + 7];
#pragma unroll
            for (int k = 0; k < 9; ++k) {
                const float4 w0 = wr[2 * k + 0];
                const float4 w1 = wr[2 * k + 1];
                const float v = w0.x * s0 + w0.y * s1 + w0.z * s2 + w0.w * s3
                              + w1.x * s4 + w1.y * s5 + w1.z * s6 + w1.w * s7;
                w_lds[buf + (k * 8 + ol) * 40 + cl] = f2h_bits(v);
            }
            __syncthreads();
            ushort* slice_base = wgen2 + (size_t)(b * 2 + mtH) * SLICE_ELEMS;
            *(uint4*)(slice_base + dst0) = *(const uint4*)(w_lds + buf + src0);
            if (tid < 32)
                *(uint4*)(slice_base + dst1) = *(const uint4*)(w_lds + buf + src1);
        }
    } else {
        // ---- gen_x ----
        const int idx = bid - PREP_GENW;
        const int hp  = idx % HP;
        const int b   = idx / HP;
        ushort* row = xpad + ((size_t)b * HP + hp) * WP * CIN;

        if (hp == 0 || hp == HP - 1) {
            uint* r32 = (uint*)row;
            for (int i = tid; i < (WP * CIN) / 2; i += 256) r32[i] = 0u;
            return;
        }
        {
            uint* c0 = (uint*)row;
            uint* c1 = (uint*)(row + (WP - 1) * CIN);
            if (tid < 128)       c0[tid] = 0u;
            else                 c1[tid - 128] = 0u;
        }
        float* lds = (float*)smem;
        const int h = hp - 1;
        const float* xr = x + (size_t)b * CIN * NPIX + h * WW;

        for (int f = tid; f < CIN * WW; f += 256) {
            const int cc = f / WW;
            const int w  = f % WW;
            lds[cc * (WW + 1) + w] = xr[(size_t)cc * NPIX + w];
        }
        __syncthreads();
        for (int g2 = tid; g2 < WW * CIN; g2 += 256) {
            const int w  = g2 >> 8;
            const int cc = g2 & 255;
            row[(w + 1) * CIN + cc] = f2h_bits(lds[cc * (WW + 1) + w]);
        }
    }
}

// ---------------------------------------------------------------------------
// dconv tile body — R8: back to the R5 2x2 wave grid (R7's 1x4 split
// regressed: DS halved but per-wave A-VMEM doubled; A-latency was the
// binding constraint). ONLY change vs R5: finer N-tiles (96 px) so the grid
// reaches 4 blocks/CU (16 waves) -- diagnosis says latency-bound with no
// pipe >50% busy, so add TLP, not scheduling.
// B-layout: plain quad*240 + pix, loop-invariant base + KOFF imms (best).
// Rings: A global->VGPR dist 2; bf LDS->VGPR dist 2; Psh dbuf; __syncthreads
// per c32; SGB order VMEM->DS->MFMA; no setprio.
// NFR BLOCK-UNIFORM (barrier safety); nt=7 runs NFR=4 with final fragment
// (px 784..799) clamped+masked.
// ---------------------------------------------------------------------------
template<int NFR>
static __device__ __forceinline__ void conv_tile(
    const ushort* __restrict__ wgen2, const ushort* __restrict__ xpad,
    const float* __restrict__ bias, float* __restrict__ out,
    ushort (*Psh)[7680], int b, int mtH, int mtl, int nt, int no, int tid)
{
    const int lane = tid & 63;
    const int wave = tid >> 6;
    const int wm   = wave >> 1;
    const int col  = lane & 15;
    const int quad = lane >> 4;

    const int mo   = mtH * 128 + mtl * 64 + wm * 32;
    const int h_lo = (nt * BN) / WW;

    const f16x8* ag = (const f16x8*)(wgen2 + (size_t)(b * 2 + mtH) * SLICE_ELEMS)
                      + (mtl * 4 + wm * 2) * 64 + lane;
    const ushort* xp = xpad + (size_t)b * HP * WP * CIN;

    int p_goff[4], p_loff[4];
    bool p_ok[4];
#pragma unroll
    for (int r = 0; r < 4; ++r) {
        const int j = r * 256 + tid;
        p_ok[r] = (j < 960);
        const int jj  = p_ok[r] ? j : 0;
        const int qc  = jj / 240;
        const int em  = jj % 240;         // identity source mapping (no swizzle)
        const int rr  = em / 30;
        const int ww  = em % 30;
        int srow = h_lo + rr;
        if (srow > 29) srow = 29;
        p_goff[r] = (srow * WP + ww) * CIN + qc * 8;
        p_loff[r] = jj * 8;               // LDS dest lane-linear (gll16 rule)
    }

    int pb[NFR], pst[NFR];
#pragma unroll
    for (int j = 0; j < NFR; ++j) {
        const int p  = no + j * 16 + col;
        pst[j] = p;
        const int pc = p > (NPIX - 1) ? (NPIX - 1) : p;   // clamp masked frags
        pb[j] = quad * 240 + (pc / WW - h_lo) * 30 + (pc % WW);
    }

    f32x4 acc[2][NFR];
#pragma unroll
    for (int mi = 0; mi < 2; ++mi)
#pragma unroll
        for (int nj = 0; nj < NFR; ++nj)
            acc[mi][nj] = (f32x4){0.f, 0.f, 0.f, 0.f};

    // ---- prologue ----
#pragma unroll
    for (int r = 0; r < 4; ++r)
        if (p_ok[r]) gll16(xp + p_goff[r], &Psh[0][p_loff[r]]);

    f16x8 afr[3][2];
#pragma unroll
    for (int mi = 0; mi < 2; ++mi) afr[0][mi] = ag[mi * 64];
    {
        const f16x8* a1 = ag + (1 << 9);
#pragma unroll
        for (int mi = 0; mi < 2; ++mi) afr[1][mi] = a1[mi * 64];
    }

    f16x8 bfr[3][NFR];

    for (int c32 = 0; c32 < 8; ++c32) {
        __syncthreads();   // patch(c32) resident; prev buffer free

        if (c32 < 7) {
            const int nb = (c32 + 1) & 1;
#pragma unroll
            for (int r = 0; r < 4; ++r)
                if (p_ok[r]) gll16(xp + p_goff[r] + (c32 + 1) * 32,
                                   &Psh[nb][p_loff[r]]);
        }

        const f16x8* Pc = (const f16x8*)Psh[c32 & 1];

        // bf ring prologue: slots 0,1 = khw 0,1 (offset-immediate reads)
#pragma unroll
        for (int j = 0; j < NFR; ++j) {
            bfr[0][j] = Pc[pb[j] + KOFF(0)];
            bfr[1][j] = Pc[pb[j] + KOFF(1)];
        }

#pragma unroll
        for (int khw = 0; khw < 9; ++khw) {
            const int st = c32 * 9 + khw;
            // A prefetch, distance 2 (slot khw%3; 9%3==0 keeps ring seamless)
            int sp = st + 2; if (sp > 71) sp = 71;
            const f16x8* apf = ag + ((size_t)sp << 9);
#pragma unroll
            for (int mi = 0; mi < 2; ++mi)
                afr[(khw + 2) % 3][mi] = apf[mi * 64];
            // bf prefetch, distance 2 (within c32)
            if (khw < 7) {
#pragma unroll
                for (int j = 0; j < NFR; ++j)
                    bfr[(khw + 2) % 3][j] = Pc[pb[j] + KOFF(khw + 2)];
            }
            // consume
#pragma unroll
            for (int mi = 0; mi < 2; ++mi)
#pragma unroll
                for (int nj = 0; nj < NFR; ++nj)
                    acc[mi][nj] = __builtin_amdgcn_mfma_f32_16x16x32_f16(
                        afr[khw % 3][mi], bfr[khw % 3][nj], acc[mi][nj], 0, 0, 0);
            // pinned pipeline (R5-proven order): VMEM -> DS -> MFMA
            __builtin_amdgcn_sched_group_barrier(0x020, 2, 0);        // VMEM_READ
            if (khw < 7)
                __builtin_amdgcn_sched_group_barrier(0x100, NFR, 0);  // DS_READ
            __builtin_amdgcn_sched_group_barrier(0x008, 2 * NFR, 0);  // MFMA
        }
    }

    // ---- epilogue (store-masked for clamped fragments) ----
    float* ob = out + (size_t)b * COUT * NPIX;
#pragma unroll
    for (int mi = 0; mi < 2; ++mi) {
        const int m = mo + mi * 16 + quad * 4;
        const float4 bv = *(const float4*)(bias + m);
#pragma unroll
        for (int nj = 0; nj < NFR; ++nj) {
            const int p = pst[nj];
            if (p < NPIX) {
                ob[(size_t)(m + 0) * NPIX + p] = acc[mi][nj][0] + bv.x;
                ob[(size_t)(m + 1) * NPIX + p] = acc[mi][nj][1] + bv.y;
                ob[(size_t)(m + 2) * NPIX + p] = acc[mi][nj][2] + bv.z;
                ob[(size_t)(m + 3) * NPIX + p] = acc[mi][nj][3] + bv.w;
            }
        }
    }
}

// ---------------------------------------------------------------------------
// dconv: grid 1024 = exactly 4 blocks/CU (16 waves/CU; was 3 blocks/12
// waves -- latency-bound regime needs TLP). 49 N-frags per (b,mtH,mtl):
// nt 0..6 carry 6 frags (2 waves x NFR=3, 96 px); nt=7 carries the last 7
// valid frags as NFR=4 on both waves (px 672..799; final frag masked).
// launch_bounds(256,4): cap regalloc at 128 VGPR for 4 waves/SIMD.
// ---------------------------------------------------------------------------
__global__ __launch_bounds__(256, 4) void dconv_mfma(const ushort* __restrict__ wgen2,
                                                     const ushort* __restrict__ xpad,
                                                     const float* __restrict__ bias,
                                                     float* __restrict__ out) {
    const int bid    = blockIdx.x;
    const int g      = bid & 7;            // XCD
    const int s      = bid >> 3;           // 0..127
    const int t      = s % 16;
    const int nt     = t % 8;
    const int mtl    = t / 8;
    const int slice2 = g + 8 * (s / 16);   // 0..63 = b*2 + mtH
    const int b      = slice2 >> 1;
    const int mtH    = slice2 & 1;
    const int tid    = threadIdx.x;
    const int wn     = (tid >> 6) & 1;

    __shared__ ushort Psh[2][7680];        // 2 x 15360 B

    if (nt == 7)   // block-uniform branch: all 4 waves take the same template
        conv_tile<4>(wgen2, xpad, bias, out, Psh, b, mtH, mtl, nt, 672 + wn * 64, tid);
    else
        conv_tile<3>(wgen2, xpad, bias, out, Psh, b, mtH, mtl, nt,
                     nt * BN + wn * 48, tid);
}

extern "C" void kernel_launch(void* const* d_in, const int* in_sizes, int n_in,
                              void* d_out, int out_size, void* d_ws, size_t ws_size,
                              hipStream_t stream) {
    const float* x      = (const float*)d_in[0];
    const float* se     = (const float*)d_in[1];
    const float* weight = (const float*)d_in[2];
    const float* bias   = (const float*)d_in[3];
    float* out          = (float*)d_out;

    ushort* wgen2 = (ushort*)d_ws;
    ushort* xpad  = (ushort*)d_ws + XPAD_OFF;
    (void)ws_size; (void)in_sizes; (void)n_in; (void)out_size;

    prep<<<dim3(PREP_GRID), dim3(256), 0, stream>>>(weight, se, x, wgen2, xpad);
    dconv_mfma<<<dim3(BB * 4 * NT), dim3(256), 0, stream>>>(wgen2, xpad, bias, out);
}

// Round 9
// 138.721 us; speedup vs baseline: 1.0698x; 1.0319x over previous
//
#include <hip/hip_runtime.h>
#include <hip/hip_fp16.h>

#define BB    32
#define CIN   256
#define COUT  256
#define HH    28
#define WW    28
#define NPIX  784
#define HP    30
#define WP    30

#define BM    128             // merged: one block covers a full (b,mtH) M-half
#define BN    96
#define NT    8               // 8 N-tiles of 96 px (nt7: 112 px, tail masked)

// workspace:
//   wgen2: fragment-ordered filters (16x16x32 MFMA), per (b,mtH) slice
//          294912 f16. Chunk (8 f16): (c32*9+khw)*512 + sub*64 + quad*16 + col
//          holds A[m = mtH*128 + sub*16 + col][ch = c32*32 + quad*8 .. +7]
//          sub 0..7 spans the full M=128 -> one block consumes the whole slice.
//   xpad : [b][30][30][256] f16 zero-padded NHWC
#define SLICE_ELEMS 294912                       // 128 * 2304
#define WGEN_ELEMS  ((size_t)BB * 2 * SLICE_ELEMS)
#define XPAD_OFF    (WGEN_ELEMS)

#define PREP_GENW  512        // (og 0..31) x (c32 0..7) x (bh 0..1)
#define PREP_GENX  960
#define PREP_GRID  (PREP_GENW + PREP_GENX)

typedef _Float16 f16x8 __attribute__((ext_vector_type(8)));
typedef float    f32x4 __attribute__((ext_vector_type(4)));

static __device__ __forceinline__ ushort f2h_bits(float v) {
    __half h = __float2half(v);
    return *reinterpret_cast<ushort*>(&h);
}

static __device__ __forceinline__ void gll16(const ushort* g, ushort* l) {
    __builtin_amdgcn_global_load_lds(
        (const __attribute__((address_space(1))) unsigned int*)g,
        (__attribute__((address_space(3))) unsigned int*)l, 16, 0, 0);
}

#define KOFF(k) (((k) / 3) * 30 + ((k) % 3))

// ---------------------------------------------------------------------------
// Fused prep kernel (unchanged).
// ---------------------------------------------------------------------------
__global__ __launch_bounds__(256) void prep(const float* __restrict__ weight,
                                            const float* __restrict__ se,
                                            const float* __restrict__ x,
                                            ushort* __restrict__ wgen2,
                                            ushort* __restrict__ xpad) {
    __shared__ __align__(16) char smem[29696];
    const int bid = blockIdx.x;
    const int tid = threadIdx.x;

    if (bid < PREP_GENW) {
        // ---- gen_w V5 ----
        const int og  = bid >> 4;
        const int bh  = (bid >> 3) & 1;
        const int c32 = bid & 7;
        const int ol  = tid >> 5;
        const int cl  = tid & 31;
        const int o   = og * 8 + ol;
        const int c   = c32 * 32 + cl;
        const int mtH = og >> 4;

        float*  se_sh = (float*)smem;                  // 1024 B
        ushort* w_lds = (ushort*)(smem + 1024);        // 2 x 2880 ushort

        se_sh[tid] = se[tid];

        float4 wr[18];
        const float4* wp = (const float4*)(weight + ((size_t)o * CIN + c) * 72);
#pragma unroll
        for (int i = 0; i < 18; ++i) wr[i] = wp[i];

        const int khw0 = tid >> 5;
        const int r0   = tid & 31;
        const int q0   = r0 >> 3;
        const int ol0  = r0 & 7;
        const int o0   = og * 8 + ol0;
        const int sub0 = (o0 >> 4) & 7, col0 = o0 & 15;
        const int dst0 = ((c32 * 9 + khw0) * 512 + sub0 * 64 + q0 * 16 + col0) * 8;
        const int src0 = (khw0 * 8 + ol0) * 40 + q0 * 8;
        const int q1   = tid >> 3;
        const int ol1  = tid & 7;
        const int o1   = og * 8 + ol1;
        const int sub1 = (o1 >> 4) & 7, col1 = o1 & 15;
        const int dst1 = ((c32 * 9 + 8) * 512 + sub1 * 64 + q1 * 16 + col1) * 8;
        const int src1 = (8 * 8 + ol1) * 40 + q1 * 8;

        __syncthreads();

        for (int bi = 0; bi < 16; ++bi) {
            const int b   = bh * 16 + bi;
            const int buf = (bi & 1) * 2880;
            const float s0 = se_sh[b * 8 + 0], s1 = se_sh[b * 8 + 1];
            const float s2 = se_sh[b * 8 + 2], s3 = se_sh[b * 8 + 3];
            const float s4 = se_sh[b * 8 + 4], s5 = se_sh[b * 8 + 5];
            const float s6 = se_sh[b * 8 + 6], s7 = se_sh[b * 8 + 7];
#pragma unroll
            for (int k = 0; k < 9; ++k) {
                const float4 w0 = wr[2 * k + 0];
                const float4 w1 = wr[2 * k + 1];
                const float v = w0.x * s0 + w0.y * s1 + w0.z * s2 + w0.w * s3
                              + w1.x * s4 + w1.y * s5 + w1.z * s6 + w1.w * s7;
                w_lds[buf + (k * 8 + ol) * 40 + cl] = f2h_bits(v);
            }
            __syncthreads();
            ushort* slice_base = wgen2 + (size_t)(b * 2 + mtH) * SLICE_ELEMS;
            *(uint4*)(slice_base + dst0) = *(const uint4*)(w_lds + buf + src0);
            if (tid < 32)
                *(uint4*)(slice_base + dst1) = *(const uint4*)(w_lds + buf + src1);
        }
    } else {
        // ---- gen_x ----
        const int idx = bid - PREP_GENW;
        const int hp  = idx % HP;
        const int b   = idx / HP;
        ushort* row = xpad + ((size_t)b * HP + hp) * WP * CIN;

        if (hp == 0 || hp == HP - 1) {
            uint* r32 = (uint*)row;
            for (int i = tid; i < (WP * CIN) / 2; i += 256) r32[i] = 0u;
            return;
        }
        {
            uint* c0 = (uint*)row;
            uint* c1 = (uint*)(row + (WP - 1) * CIN);
            if (tid < 128)       c0[tid] = 0u;
            else                 c1[tid - 128] = 0u;
        }
        float* lds = (float*)smem;
        const int h = hp - 1;
        const float* xr = x + (size_t)b * CIN * NPIX + h * WW;

        for (int f = tid; f < CIN * WW; f += 256) {
            const int cc = f / WW;
            const int w  = f % WW;
            lds[cc * (WW + 1) + w] = xr[(size_t)cc * NPIX + w];
        }
        __syncthreads();
        for (int g2 = tid; g2 < WW * CIN; g2 += 256) {
            const int w  = g2 >> 8;
            const int cc = g2 & 255;
            row[(w + 1) * CIN + cc] = f2h_bits(lds[cc * (WW + 1) + w]);
        }
    }
}

// ---------------------------------------------------------------------------
// dconv tile body — R9: 512-thread 8-wave block, M=128 (mtl merged away).
// Diagnosis from R5 vs R8 (same structure, 768 vs 1024 blocks): ~50% of
// block time is PER-BLOCK FIXED cost (30KB staging patch per c32 regardless
// of tile width, prologue, 8 barrier convergences). Merging the two mtl
// blocks halves staging bytes per output and cuts block count 768->512
// (= exactly 2 blocks/CU, 16 waves/CU) while keeping the R5-best per-wave
// shape. Wave grid 4wm x 2wn; wave = M=32 (sub wm*2+mi) x N=NFR*16.
// All scheduling/layout frozen at R5 measured best: plain-240 + KOFF imms,
// SGB order VMEM->DS->MFMA, __syncthreads per c32, no setprio, rings dist 2.
// NFR BLOCK-UNIFORM; nt=7 runs NFR=4 with final fragment clamped+masked.
// ---------------------------------------------------------------------------
template<int NFR>
static __device__ __forceinline__ void conv_tile(
    const ushort* __restrict__ wgen2, const ushort* __restrict__ xpad,
    const float* __restrict__ bias, float* __restrict__ out,
    ushort (*Psh)[7680], int b, int mtH, int nt, int no, int tid)
{
    const int lane = tid & 63;
    const int wave = tid >> 6;          // 0..7
    const int wm   = wave >> 1;         // 0..3
    const int col  = lane & 15;
    const int quad = lane >> 4;

    const int mo   = mtH * 128 + wm * 32;
    const int h_lo = (nt * BN) / WW;

    // A frag mi at K-step st: (st<<9) + (wm*2+mi)*64 + lane
    const f16x8* ag = (const f16x8*)(wgen2 + (size_t)(b * 2 + mtH) * SLICE_ELEMS)
                      + (wm * 2) * 64 + lane;
    const ushort* xp = xpad + (size_t)b * HP * WP * CIN;

    int p_goff[2], p_loff[2];
    bool p_ok[2];
#pragma unroll
    for (int r = 0; r < 2; ++r) {
        const int j = r * 512 + tid;
        p_ok[r] = (j < 960);
        const int jj  = p_ok[r] ? j : 0;
        const int qc  = jj / 240;
        const int em  = jj % 240;         // identity source mapping (no swizzle)
        const int rr  = em / 30;
        const int ww  = em % 30;
        int srow = h_lo + rr;
        if (srow > 29) srow = 29;
        p_goff[r] = (srow * WP + ww) * CIN + qc * 8;
        p_loff[r] = jj * 8;               // LDS dest lane-linear (gll16 rule)
    }

    int pb[NFR], pst[NFR];
#pragma unroll
    for (int j = 0; j < NFR; ++j) {
        const int p  = no + j * 16 + col;
        pst[j] = p;
        const int pc = p > (NPIX - 1) ? (NPIX - 1) : p;   // clamp masked frags
        pb[j] = quad * 240 + (pc / WW - h_lo) * 30 + (pc % WW);
    }

    f32x4 acc[2][NFR];
#pragma unroll
    for (int mi = 0; mi < 2; ++mi)
#pragma unroll
        for (int nj = 0; nj < NFR; ++nj)
            acc[mi][nj] = (f32x4){0.f, 0.f, 0.f, 0.f};

    // ---- prologue ----
#pragma unroll
    for (int r = 0; r < 2; ++r)
        if (p_ok[r]) gll16(xp + p_goff[r], &Psh[0][p_loff[r]]);

    f16x8 afr[3][2];
#pragma unroll
    for (int mi = 0; mi < 2; ++mi) afr[0][mi] = ag[mi * 64];
    {
        const f16x8* a1 = ag + (1 << 9);
#pragma unroll
        for (int mi = 0; mi < 2; ++mi) afr[1][mi] = a1[mi * 64];
    }

    f16x8 bfr[3][NFR];

    for (int c32 = 0; c32 < 8; ++c32) {
        __syncthreads();   // patch(c32) resident; prev buffer free

        if (c32 < 7) {
            const int nb = (c32 + 1) & 1;
#pragma unroll
            for (int r = 0; r < 2; ++r)
                if (p_ok[r]) gll16(xp + p_goff[r] + (c32 + 1) * 32,
                                   &Psh[nb][p_loff[r]]);
        }

        const f16x8* Pc = (const f16x8*)Psh[c32 & 1];

        // bf ring prologue: slots 0,1 = khw 0,1 (offset-immediate reads)
#pragma unroll
        for (int j = 0; j < NFR; ++j) {
            bfr[0][j] = Pc[pb[j] + KOFF(0)];
            bfr[1][j] = Pc[pb[j] + KOFF(1)];
        }

#pragma unroll
        for (int khw = 0; khw < 9; ++khw) {
            const int st = c32 * 9 + khw;
            // A prefetch, distance 2 (slot khw%3; 9%3==0 keeps ring seamless)
            int sp = st + 2; if (sp > 71) sp = 71;
            const f16x8* apf = ag + ((size_t)sp << 9);
#pragma unroll
            for (int mi = 0; mi < 2; ++mi)
                afr[(khw + 2) % 3][mi] = apf[mi * 64];
            // bf prefetch, distance 2 (within c32)
            if (khw < 7) {
#pragma unroll
                for (int j = 0; j < NFR; ++j)
                    bfr[(khw + 2) % 3][j] = Pc[pb[j] + KOFF(khw + 2)];
            }
            // consume
#pragma unroll
            for (int mi = 0; mi < 2; ++mi)
#pragma unroll
                for (int nj = 0; nj < NFR; ++nj)
                    acc[mi][nj] = __builtin_amdgcn_mfma_f32_16x16x32_f16(
                        afr[khw % 3][mi], bfr[khw % 3][nj], acc[mi][nj], 0, 0, 0);
            // pinned pipeline (R5-proven order): VMEM -> DS -> MFMA
            __builtin_amdgcn_sched_group_barrier(0x020, 2, 0);        // VMEM_READ
            if (khw < 7)
                __builtin_amdgcn_sched_group_barrier(0x100, NFR, 0);  // DS_READ
            __builtin_amdgcn_sched_group_barrier(0x008, 2 * NFR, 0);  // MFMA
        }
    }

    // ---- epilogue (store-masked for clamped fragments) ----
    float* ob = out + (size_t)b * COUT * NPIX;
#pragma unroll
    for (int mi = 0; mi < 2; ++mi) {
        const int m = mo + mi * 16 + quad * 4;
        const float4 bv = *(const float4*)(bias + m);
#pragma unroll
        for (int nj = 0; nj < NFR; ++nj) {
            const int p = pst[nj];
            if (p < NPIX) {
                ob[(size_t)(m + 0) * NPIX + p] = acc[mi][nj][0] + bv.x;
                ob[(size_t)(m + 1) * NPIX + p] = acc[mi][nj][1] + bv.y;
                ob[(size_t)(m + 2) * NPIX + p] = acc[mi][nj][2] + bv.z;
                ob[(size_t)(m + 3) * NPIX + p] = acc[mi][nj][3] + bv.w;
            }
        }
    }
}

// ---------------------------------------------------------------------------
// dconv: 512 blocks x 512 threads = exactly 2 blocks/CU (16 waves/CU).
// Decode: g = XCD; 64 s-values per XCD -> nt = s&7, slice2 = g + 8*(s>>3);
// 8 blocks per (b,mtH) slice on the SAME XCD -> A-stream L2/L1 locality.
// nt 0..6: NFR=3 (96 px, no = nt*96 + wn*48); nt=7: NFR=4 (px 672..799,
// final fragment clamped+masked). launch_bounds(512,4): 4 waves/SIMD cap.
// ---------------------------------------------------------------------------
__global__ __launch_bounds__(512, 4) void dconv_mfma(const ushort* __restrict__ wgen2,
                                                     const ushort* __restrict__ xpad,
                                                     const float* __restrict__ bias,
                                                     float* __restrict__ out) {
    const int bid    = blockIdx.x;
    const int g      = bid & 7;            // XCD
    const int s      = bid >> 3;           // 0..63
    const int nt     = s & 7;
    const int slice2 = g + 8 * (s >> 3);   // 0..63 = b*2 + mtH
    const int b      = slice2 >> 1;
    const int mtH    = slice2 & 1;
    const int tid    = threadIdx.x;
    const int wn     = (tid >> 6) & 1;

    __shared__ ushort Psh[2][7680];        // 2 x 15360 B

    if (nt == 7)   // block-uniform branch: all 8 waves take the same template
        conv_tile<4>(wgen2, xpad, bias, out, Psh, b, mtH, nt, 672 + wn * 64, tid);
    else
        conv_tile<3>(wgen2, xpad, bias, out, Psh, b, mtH, nt,
                     nt * BN + wn * 48, tid);
}

extern "C" void kernel_launch(void* const* d_in, const int* in_sizes, int n_in,
                              void* d_out, int out_size, void* d_ws, size_t ws_size,
                              hipStream_t stream) {
    const float* x      = (const float*)d_in[0];
    const float* se     = (const float*)d_in[1];
    const float* weight = (const float*)d_in[2];
    const float* bias   = (const float*)d_in[3];
    float* out          = (float*)d_out;

    ushort* wgen2 = (ushort*)d_ws;
    ushort* xpad  = (ushort*)d_ws + XPAD_OFF;
    (void)ws_size; (void)in_sizes; (void)n_in; (void)out_size;

    prep<<<dim3(PREP_GRID), dim3(256), 0, stream>>>(weight, se, x, wgen2, xpad);
    dconv_mfma<<<dim3(BB * 2 * NT), dim3(512), 0, stream>>>(wgen2, xpad, bias, out);
}